// Round 9
// baseline (354.897 us; speedup 1.0000x reference)
//
#include <hip/hip_runtime.h>

#define NU 4096
#define NI 4096
#define NR 3
#define NB 512
#define NL 100
#define FEPS 1e-8f

// workspace layout (float offsets)
#define WS_SI    0            // [NI*128]   s_i: [i][k*32+d]
#define WS_EMBW  524288       // [3*NI*128] iemb @ ipW[r]
#define WS_TIP   2097152      // [3*NI*128] tip per relation
#define WS_UEW   3670016      // [NU*128]   user_embedding @ W
#define WS_ITEMF 4194304      // [NI*128]   item_feature
#define WS_PROJ  4915200      // [NB*3*128] proj per (b,r)
#define WS_UF    5111808      // [NB*128]   uf_sel
#define WS_BMT   5190656      // [64*4096 ulong = 2MB] transposed bitmask of tm

// ---------------------------------------------------------------------------
// K1 k_bmm_si: bid<1024: batched GEMM [4096,128]@[128,128] (b0-2 embW[r]=iemb@ipW[r],
// b3 uew=uemb@W); bid>=1024 (2048 blocks): s_i for 2 items per block.
// Block 0 thread 0 zeroes the L2-loss accumulator out[51200].
__global__ void k_bmm_si(const float* __restrict__ iemb, const float* __restrict__ ipW,
                         const float* __restrict__ uemb, const float* __restrict__ Wm,
                         const float* __restrict__ WK, const float* __restrict__ BK,
                         float* __restrict__ embW, float* __restrict__ uew,
                         float* __restrict__ si, float* __restrict__ out) {
  int t = threadIdx.x;  // 256
  int bid = blockIdx.x;
  if (bid == 0 && t == 0) out[NB * NL] = 0.f;
  if (bid < 1024) {
    __shared__ __align__(16) float shbuf[2048];
    int batch = bid >> 8, rb = bid & 255;  // 16 rows per block
    const float* in;
    const float* Wp;
    float* outp;
    if (batch < 3) {
      in = iemb;
      Wp = ipW + (size_t)batch * 16384;
      outp = embW + (size_t)batch * NI * 128;
    } else {
      in = uemb; Wp = Wm; outp = uew;
    }
    const float4* in4 = (const float4*)(in + (size_t)rb * 2048);
    for (int c = t; c < 512; c += 256) ((float4*)shbuf)[c] = in4[c];
    __syncthreads();
    int c = t & 127, g = t >> 7;
    float acc[8];
#pragma unroll
    for (int rr = 0; rr < 8; ++rr) acc[rr] = 0.f;
    for (int e = 0; e < 128; ++e) {
      float wv = Wp[e * 128 + c];
#pragma unroll
      for (int rr = 0; rr < 8; ++rr) acc[rr] += shbuf[(g * 8 + rr) * 128 + e] * wv;
    }
#pragma unroll
    for (int rr = 0; rr < 8; ++rr) outp[((size_t)rb * 16 + g * 8 + rr) * 128 + c] = acc[rr];
  } else {
    __shared__ __align__(16) float embs2[256];
    int tl = t & 127, half = t >> 7;
    int item = (bid - 1024) * 2 + half;
    float* embs = embs2 + half * 128;
    if (tl < 32) ((float4*)embs)[tl] = ((const float4*)(iemb + (size_t)item * 128))[tl];
    __syncthreads();
    float acc = BK[tl];
    const float4* wk4 = (const float4*)(WK + (size_t)tl * 128);
    const float4* e4 = (const float4*)embs;
#pragma unroll 8
    for (int cc = 0; cc < 32; ++cc) {
      float4 w = wk4[cc], v = e4[cc];
      acc += w.x * v.x + w.y * v.y + w.z * v.z + w.w * v.w;
    }
    acc = fmaxf(acc, 0.f);
    float sq = acc * acc;
#pragma unroll
    for (int m = 1; m <= 16; m <<= 1) sq += __shfl_xor(sq, m);
    si[(size_t)item * 128 + tl] = acc / fmaxf(sqrtf(sq), 1e-12f);
  }
}

// ---------------------------------------------------------------------------
// K2 k_scan: bid<4096: tm row -> bmT bits (loads hoisted).
// bid>=4096 (6144 blocks): TWO G rows each: 8 hoisted loads -> nz lists ->
// gather embW -> tip, two phases.
__global__ void k_scan(const float* __restrict__ tm, const float* __restrict__ G,
                       const float* __restrict__ deg, const float* __restrict__ embW,
                       unsigned long long* __restrict__ bmT, float* __restrict__ tip) {
  int t = threadIdx.x;  // 256
  int bid = blockIdx.x;
  if (bid < 4096) {
    __shared__ unsigned char nib[4][256];
    const float4* r4 = (const float4*)(tm + (size_t)bid * NI);
    float4 v0 = r4[t], v1 = r4[256 + t], v2 = r4[512 + t], v3 = r4[768 + t];
#pragma unroll
    for (int q = 0; q < 4; ++q) {
      float4 v = (q == 0) ? v0 : (q == 1) ? v1 : (q == 2) ? v2 : v3;
      unsigned m = 0;
      if (v.x != 0.f) m |= 1u;
      if (v.y != 0.f) m |= 2u;
      if (v.z != 0.f) m |= 4u;
      if (v.w != 0.f) m |= 8u;
      nib[q][t] = (unsigned char)m;
    }
    __syncthreads();
    if (t < 64) {
      unsigned long long mm = 0;
#pragma unroll
      for (int j = 0; j < 16; ++j) {
        int e = t * 16 + j;  // float4 index within row
        mm |= (unsigned long long)nib[e >> 8][e & 255] << (4 * j);
      }
      bmT[(size_t)t * NU + bid] = mm;
    }
  } else {
    int gid0 = (bid - 4096) * 2;  // first of two G rows
    __shared__ int nzA[512], nzB[512];
    __shared__ int cntA, cntB;
    __shared__ float4 red[8][32];
    if (t == 0) { cntA = 0; cntB = 0; }
    __syncthreads();
    const float4* rowA = (const float4*)(G + (size_t)gid0 * NI);
    const float4* rowB = (const float4*)(G + (size_t)(gid0 + 1) * NI);
    // hoist all 8 loads (independent)
    float4 a0 = rowA[t], a1 = rowA[256 + t], a2 = rowA[512 + t], a3 = rowA[768 + t];
    float4 b0 = rowB[t], b1 = rowB[256 + t], b2 = rowB[512 + t], b3 = rowB[768 + t];
#pragma unroll
    for (int c = 0; c < 4; ++c) {
      float4 v = (c == 0) ? a0 : (c == 1) ? a1 : (c == 2) ? a2 : a3;
      int j0 = (c * 256 + t) << 2;
      if (v.x != 0.f) nzA[atomicAdd(&cntA, 1)] = j0;
      if (v.y != 0.f) nzA[atomicAdd(&cntA, 1)] = j0 + 1;
      if (v.z != 0.f) nzA[atomicAdd(&cntA, 1)] = j0 + 2;
      if (v.w != 0.f) nzA[atomicAdd(&cntA, 1)] = j0 + 3;
    }
#pragma unroll
    for (int c = 0; c < 4; ++c) {
      float4 v = (c == 0) ? b0 : (c == 1) ? b1 : (c == 2) ? b2 : b3;
      int j0 = (c * 256 + t) << 2;
      if (v.x != 0.f) nzB[atomicAdd(&cntB, 1)] = j0;
      if (v.y != 0.f) nzB[atomicAdd(&cntB, 1)] = j0 + 1;
      if (v.z != 0.f) nzB[atomicAdd(&cntB, 1)] = j0 + 2;
      if (v.w != 0.f) nzB[atomicAdd(&cntB, 1)] = j0 + 3;
    }
    __syncthreads();
    int g = t >> 5, f = t & 31;  // 8 neighbor-slots x 32 lanes (float4 each)
    // phase A
    {
      int r = gid0 >> 12;
      int n = min(cntA, 512);
      float4 acc = {0.f, 0.f, 0.f, 0.f};
      const float4* e4 = (const float4*)(embW + (size_t)r * NI * 128);
      for (int p = g; p < n; p += 8) {
        float4 v = e4[(size_t)nzA[p] * 32 + f];
        acc.x += v.x; acc.y += v.y; acc.z += v.z; acc.w += v.w;
      }
      red[g][f] = acc;
      __syncthreads();
      if (t < 32) {
        float4 s = red[0][t];
#pragma unroll
        for (int q = 1; q < 8; ++q) {
          float4 v = red[q][t];
          s.x += v.x; s.y += v.y; s.z += v.z; s.w += v.w;
        }
        float inv = 1.f / (deg[gid0] + FEPS);
        s.x *= inv; s.y *= inv; s.z *= inv; s.w *= inv;
        ((float4*)(tip + (size_t)gid0 * 128))[t] = s;
      }
      __syncthreads();
    }
    // phase B
    {
      int r = (gid0 + 1) >> 12;
      int n = min(cntB, 512);
      float4 acc = {0.f, 0.f, 0.f, 0.f};
      const float4* e4 = (const float4*)(embW + (size_t)r * NI * 128);
      for (int p = g; p < n; p += 8) {
        float4 v = e4[(size_t)nzB[p] * 32 + f];
        acc.x += v.x; acc.y += v.y; acc.z += v.z; acc.w += v.w;
      }
      red[g][f] = acc;
      __syncthreads();
      if (t < 32) {
        float4 s = red[0][t];
#pragma unroll
        for (int q = 1; q < 8; ++q) {
          float4 v = red[q][t];
          s.x += v.x; s.y += v.y; s.z += v.z; s.w += v.w;
        }
        float inv = 1.f / (deg[gid0 + 1] + FEPS);
        s.x *= inv; s.y *= inv; s.z *= inv; s.w *= inv;
        ((float4*)(tip + (size_t)(gid0 + 1) * 128))[t] = s;
      }
    }
  }
}

// ---------------------------------------------------------------------------
// K3 k_userf: bid<4096: itemf[i] via bmT column CSC.
// bid>=4096 (512 blocks): fused per-b user pipeline (3 relations) + uf=comb@W;
// uf^2 accumulated into out[51200] via atomicAdd (scaled 1e-4*100).
__global__ void k_userf(const unsigned long long* __restrict__ bmT,
                        const float* __restrict__ uew, float* __restrict__ itemf,
                        const int* __restrict__ user, const float* __restrict__ relm,
                        const float* __restrict__ si, const float* __restrict__ tip,
                        const float* __restrict__ uemb, const float* __restrict__ WK,
                        const float* __restrict__ BK, const float* __restrict__ ibW,
                        const float* __restrict__ ubd, const float* __restrict__ mw,
                        const float* __restrict__ Wm, float* __restrict__ proj,
                        float* __restrict__ uf, float* __restrict__ out) {
  int t = threadIdx.x;  // 256
  int bid = blockIdx.x;
  if (bid < 4096) {
    int i = bid;  // item
    int ct = i >> 6;
    unsigned long long bitm = 1ull << (i & 63);
    __shared__ int lst[192];
    __shared__ int cnt2;
    __shared__ float red2[3][128];
    if (t == 0) cnt2 = 0;
    __syncthreads();
    const unsigned long long* col = bmT + (size_t)ct * NU;
#pragma unroll
    for (int cc = 0; cc < 16; ++cc) {
      unsigned long long m = col[cc * 256 + t];
      if (m & bitm) lst[atomicAdd(&cnt2, 1)] = cc * 256 + t;
    }
    __syncthreads();
    int n = min(cnt2, 192);
    int w = t >> 6, l = t & 63;
    float ax = 0.f, ay = 0.f;
    const float2* uew2 = (const float2*)uew;
    for (int p = w; p < n; p += 4) {
      float2 v = uew2[(size_t)lst[p] * 64 + l];
      ax += v.x; ay += v.y;
    }
    if (w > 0) { red2[w - 1][2 * l] = ax; red2[w - 1][2 * l + 1] = ay; }
    __syncthreads();
    if (w == 0) {
      float2 o;
      o.x = ax + red2[0][2 * l] + red2[1][2 * l] + red2[2][2 * l];
      o.y = ay + red2[0][2 * l + 1] + red2[1][2 * l + 1] + red2[2][2 * l + 1];
      ((float2*)(itemf + (size_t)i * 128))[l] = o;
    }
  } else {
    int b = bid - 4096;
    int u = user[b];
    __shared__ int nz[512];
    __shared__ int cnt;
    __shared__ __align__(16) float uel[128];
    __shared__ float su0[128];
    __shared__ float comb[128];
    __shared__ float tu[128];
    __shared__ float redA[4][128];
    __shared__ float redB[4][128];
    __shared__ float part[2];
    if (t < 32) ((float4*)uel)[t] = ((const float4*)(uemb + (size_t)u * 128))[t];
    __syncthreads();
    if (t < 128) {
      float a = BK[t];
      const float4* wk4 = (const float4*)(WK + (size_t)t * 128);
      const float4* ue4 = (const float4*)uel;
#pragma unroll 8
      for (int c = 0; c < 32; ++c) {
        float4 w = wk4[c], v = ue4[c];
        a += w.x * v.x + w.y * v.y + w.z * v.z + w.w * v.w;
      }
      a = fmaxf(a, 0.f);
      float sq = a * a;
#pragma unroll
      for (int m = 1; m <= 16; m <<= 1) sq += __shfl_xor(sq, m);
      su0[t] = a / fmaxf(sqrtf(sq), 1e-12f);
      comb[t] = 0.f;
    }
    float d0 = ubd[u * 3], d1 = ubd[u * 3 + 1], d2 = ubd[u * 3 + 2];
    float w0 = mw[0], w1 = mw[1], w2 = mw[2];
    float tw = d0 * w0 + d1 * w1 + d2 * w2;
    int wid = t >> 6, lane = t & 63;
    int k = lane >> 4;
    const float2* si2 = (const float2*)si;
    for (int r = 0; r < 3; ++r) {
      if (t == 0) cnt = 0;
      __syncthreads();
      const float4* rel4 = (const float4*)(relm + ((size_t)r * NU + u) * NI);
      float4 q0 = rel4[t], q1 = rel4[256 + t], q2 = rel4[512 + t], q3 = rel4[768 + t];
#pragma unroll
      for (int c = 0; c < 4; ++c) {
        float4 v = (c == 0) ? q0 : (c == 1) ? q1 : (c == 2) ? q2 : q3;
        int j0 = (c * 256 + t) << 2;
        if (v.x != 0.f) nz[atomicAdd(&cnt, 1)] = j0;
        if (v.y != 0.f) nz[atomicAdd(&cnt, 1)] = j0 + 1;
        if (v.z != 0.f) nz[atomicAdd(&cnt, 1)] = j0 + 2;
        if (v.w != 0.f) nz[atomicAdd(&cnt, 1)] = j0 + 3;
      }
      __syncthreads();
      int n = min(cnt, 512);
      float2 myue = ((const float2*)uel)[lane];
      float sux = 0.f, suy = 0.f, tpx = 0.f, tpy = 0.f;
      const float2* tip2 = (const float2*)(tip + (size_t)r * NI * 128);
      for (int p = wid; p < n; p += 4) {
        int i = nz[p];
        float2 sv = si2[(size_t)i * 64 + lane];
        float lg = myue.x * sv.x + myue.y * sv.y;
        lg += __shfl_xor(lg, 1);
        lg += __shfl_xor(lg, 2);
        lg += __shfl_xor(lg, 4);
        lg += __shfl_xor(lg, 8);
        float l0 = __shfl(lg, 0), l1 = __shfl(lg, 16), l2 = __shfl(lg, 32), l3 = __shfl(lg, 48);
        float mx = fmaxf(fmaxf(l0, l1), fmaxf(l2, l3));
        float e0 = __expf(l0 - mx), e1 = __expf(l1 - mx), e2 = __expf(l2 - mx), e3 = __expf(l3 - mx);
        float inv = 1.f / (e0 + e1 + e2 + e3);
        float myr = (k == 0 ? e0 : k == 1 ? e1 : k == 2 ? e2 : e3) * inv;
        sux += myr * sv.x;
        suy += myr * sv.y;
        float2 tv = tip2[(size_t)i * 64 + lane];
        tpx += tv.x;
        tpy += tv.y;
      }
      redA[wid][2 * lane] = sux; redA[wid][2 * lane + 1] = suy;
      redB[wid][2 * lane] = tpx; redB[wid][2 * lane + 1] = tpy;
      __syncthreads();
      if (t < 128) {
        float suv = redA[0][t] + redA[1][t] + redA[2][t] + redA[3][t];
        float tipv = redB[0][t] + redB[1][t] + redB[2][t] + redB[3][t];
        float su = su0[t] + suv;
        float sq2 = su * su;
#pragma unroll
        for (int m = 1; m <= 16; m <<= 1) sq2 += __shfl_xor(sq2, m);
        float tun = su / fmaxf(sqrtf(sq2), 1e-12f);
        float dr = (r == 0 ? d0 : r == 1 ? d1 : d2);
        float wr = (r == 0 ? w0 : r == 1 ? w1 : w2);
        comb[t] += (dr * wr / (tw + FEPS)) * tun;
        tu[t] = tipv / (dr + FEPS);
      }
      __syncthreads();
      int ep = t & 127, hh = t >> 7;
      const float* Wb = ibW + (size_t)r * 16384;
      float pacc = 0.f;
      for (int e = hh * 64; e < hh * 64 + 64; ++e) pacc += tu[e] * Wb[e * 128 + ep];
      redA[hh][ep] = pacc;
      __syncthreads();
      if (hh == 0) proj[(size_t)(b * 3 + r) * 128 + ep] = redA[0][ep] + redA[1][ep];
      __syncthreads();
    }
    if (t < 128) {
      float acc = 0.f;
      for (int e = 0; e < 128; ++e) acc += comb[e] * Wm[e * 128 + t];
      uf[(size_t)b * 128 + t] = acc;
      float sq = acc * acc;
#pragma unroll
      for (int m = 1; m <= 32; m <<= 1) sq += __shfl_xor(sq, m);
      if ((t & 63) == 0) part[t >> 6] = sq;
    }
    __syncthreads();
    if (t == 0) atomicAdd(&out[NB * NL], 0.01f * (part[0] + part[1]));
  }
}

// ---------------------------------------------------------------------------
// K4: one wave per (b,l): score1 + LAMB*score2/R ; itf^2 atomically into out[51200]
__global__ void k_score(const int* __restrict__ item, const float* __restrict__ itemf,
                        const float* __restrict__ uf, const float* __restrict__ tip,
                        const float* __restrict__ proj, float* __restrict__ out) {
  int t = threadIdx.x, wid = t >> 6, lane = t & 63;
  int idx = blockIdx.x * 4 + wid;  // < 51200
  int b = idx / NL;
  int it = item[idx];
  float2 av = ((const float2*)(itemf + (size_t)it * 128))[lane];
  float2 cv = ((const float2*)(uf + (size_t)b * 128))[lane];
  float s1 = av.x * cv.x + av.y * cv.y;
  float sqi = av.x * av.x + av.y * av.y;
  float s2 = 0.f;
#pragma unroll
  for (int r = 0; r < 3; ++r) {
    float2 tv = ((const float2*)(tip + ((size_t)r * NI + it) * 128))[lane];
    float2 pv = ((const float2*)(proj + (size_t)(b * 3 + r) * 128))[lane];
    s2 += tv.x * pv.x + tv.y * pv.y;
  }
#pragma unroll
  for (int m = 1; m <= 32; m <<= 1) {
    s1 += __shfl_xor(s1, m);
    s2 += __shfl_xor(s2, m);
    sqi += __shfl_xor(sqi, m);
  }
  if (lane == 0) out[idx] = s1 + 0.5f * (s2 * (1.f / 3.f));
  __shared__ float sh[4];
  if (lane == 0) sh[wid] = sqi;
  __syncthreads();
  if (t == 0) atomicAdd(&out[NB * NL], 1e-4f * (sh[0] + sh[1] + sh[2] + sh[3]));
}

// ---------------------------------------------------------------------------
extern "C" void kernel_launch(void* const* d_in, const int* in_sizes, int n_in,
                              void* d_out, int out_size, void* d_ws, size_t ws_size,
                              hipStream_t stream) {
  (void)in_sizes; (void)n_in; (void)out_size; (void)ws_size;
  const int* user = (const int*)d_in[0];
  const int* item = (const int*)d_in[1];
  const float* uemb = (const float*)d_in[2];
  const float* iemb = (const float*)d_in[3];
  const float* mw = (const float*)d_in[4];
  const float* ibW = (const float*)d_in[5];
  const float* ipW = (const float*)d_in[6];
  const float* Wm = (const float*)d_in[7];
  const float* WK = (const float*)d_in[8];
  const float* BK = (const float*)d_in[9];
  const float* tm = (const float*)d_in[10];
  const float* relm = (const float*)d_in[11];
  const float* ig = (const float*)d_in[12];
  const float* igd = (const float*)d_in[13];
  const float* ubd = (const float*)d_in[14];
  float* out = (float*)d_out;
  float* ws = (float*)d_ws;
  unsigned long long* bmT = (unsigned long long*)(ws + WS_BMT);

  k_bmm_si<<<3072, 256, 0, stream>>>(iemb, ipW, uemb, Wm, WK, BK,
                                     ws + WS_EMBW, ws + WS_UEW, ws + WS_SI, out);
  k_scan<<<10240, 256, 0, stream>>>(tm, ig, igd, ws + WS_EMBW, bmT, ws + WS_TIP);
  k_userf<<<4608, 256, 0, stream>>>(bmT, ws + WS_UEW, ws + WS_ITEMF, user, relm,
                                    ws + WS_SI, ws + WS_TIP, uemb, WK, BK, ibW,
                                    ubd, mw, Wm, ws + WS_PROJ, ws + WS_UF, out);
  k_score<<<12800, 256, 0, stream>>>(item, ws + WS_ITEMF, ws + WS_UF, ws + WS_TIP,
                                     ws + WS_PROJ, out);
}

// Round 10
// 191.380 us; speedup vs baseline: 1.8544x; 1.8544x over previous
//
#include <hip/hip_runtime.h>

#define NU 4096
#define NI 4096
#define NR 3
#define NB 512
#define NL 100
#define FEPS 1e-8f

// workspace layout (float offsets)
#define WS_SI    0            // [NI*128]   s_i: [i][k*32+d]
#define WS_EMBW  524288       // [3*NI*128] iemb @ ipW[r]
#define WS_TIP   2097152      // [3*NI*128] tip per relation
#define WS_UEW   3670016      // [NU*128]   user_embedding @ W
#define WS_ITEMF 4194304      // [NI*128]   item_feature
#define WS_WTUN  4718592      // [NB*3*128] ubw-weighted tun per (b,r)
#define WS_PROJ  4915200      // [NB*3*128] proj per (b,r)
#define WS_UF    5111808      // [NB*128]   uf_sel
#define WS_UF2P  5177344      // [NB]       per-b uf^2 partials
#define WS_ITF2P 5177856      // [12800]    per-block itf^2 partials
#define WS_BMT   5190656      // [64*4096 ulong = 2MB] transposed bitmask of tm

// ---------------------------------------------------------------------------
// K1 k_prep: bid<4096: tm row -> bmT bits; bid<5120: batched GEMM
// (b0-2 embW[r]=iemb@ipW[r], b3 uew=uemb@W); bid<7168: s_i, 2 items/block.
// All three branches mutually independent (no intra-launch deps).
__global__ void k_prep(const float* __restrict__ iemb, const float* __restrict__ ipW,
                       const float* __restrict__ uemb, const float* __restrict__ Wm,
                       const float* __restrict__ WK, const float* __restrict__ BK,
                       const float* __restrict__ tm,
                       float* __restrict__ embW, float* __restrict__ uew,
                       float* __restrict__ si, unsigned long long* __restrict__ bmT) {
  int t = threadIdx.x;  // 256
  int bid = blockIdx.x;
  if (bid < 4096) {
    __shared__ unsigned char nib[4][256];
    const float4* r4 = (const float4*)(tm + (size_t)bid * NI);
#pragma unroll
    for (int q = 0; q < 4; ++q) {
      float4 v = r4[q * 256 + t];
      unsigned m = 0;
      if (v.x != 0.f) m |= 1u;
      if (v.y != 0.f) m |= 2u;
      if (v.z != 0.f) m |= 4u;
      if (v.w != 0.f) m |= 8u;
      nib[q][t] = (unsigned char)m;
    }
    __syncthreads();
    if (t < 64) {
      unsigned long long mm = 0;
#pragma unroll
      for (int j = 0; j < 16; ++j) {
        int e = t * 16 + j;  // float4 index within row
        mm |= (unsigned long long)nib[e >> 8][e & 255] << (4 * j);
      }
      bmT[(size_t)t * NU + bid] = mm;
    }
  } else if (bid < 5120) {
    __shared__ __align__(16) float shbuf[2048];
    int lb = bid - 4096;
    int batch = lb >> 8, rb = lb & 255;  // 16 rows per block
    const float* in;
    const float* Wp;
    float* outp;
    if (batch < 3) {
      in = iemb;
      Wp = ipW + (size_t)batch * 16384;
      outp = embW + (size_t)batch * NI * 128;
    } else {
      in = uemb; Wp = Wm; outp = uew;
    }
    const float4* in4 = (const float4*)(in + (size_t)rb * 2048);
    for (int c = t; c < 512; c += 256) ((float4*)shbuf)[c] = in4[c];
    __syncthreads();
    int c = t & 127, g = t >> 7;
    float acc[8];
#pragma unroll
    for (int rr = 0; rr < 8; ++rr) acc[rr] = 0.f;
    for (int e = 0; e < 128; ++e) {
      float wv = Wp[e * 128 + c];
#pragma unroll
      for (int rr = 0; rr < 8; ++rr) acc[rr] += shbuf[(g * 8 + rr) * 128 + e] * wv;
    }
#pragma unroll
    for (int rr = 0; rr < 8; ++rr) outp[((size_t)rb * 16 + g * 8 + rr) * 128 + c] = acc[rr];
  } else {
    __shared__ __align__(16) float embs2[256];
    int tl = t & 127, half = t >> 7;
    int item = (bid - 5120) * 2 + half;
    float* embs = embs2 + half * 128;
    if (tl < 32) ((float4*)embs)[tl] = ((const float4*)(iemb + (size_t)item * 128))[tl];
    __syncthreads();
    float acc = BK[tl];
    const float4* wk4 = (const float4*)(WK + (size_t)tl * 128);
    const float4* e4 = (const float4*)embs;
#pragma unroll 8
    for (int cc = 0; cc < 32; ++cc) {
      float4 w = wk4[cc], v = e4[cc];
      acc += w.x * v.x + w.y * v.y + w.z * v.z + w.w * v.w;
    }
    acc = fmaxf(acc, 0.f);
    float sq = acc * acc;
#pragma unroll
    for (int m = 1; m <= 16; m <<= 1) sq += __shfl_xor(sq, m);
    si[(size_t)item * 128 + tl] = acc / fmaxf(sqrtf(sq), 1e-12f);
  }
}

// ---------------------------------------------------------------------------
// K2 k_scan: one G row per block (r*4096+i): scan -> nz list -> gather embW[r]
// -> tip[r][i].  (R4 champion G-branch, verbatim.)
__global__ void k_scan(const float* __restrict__ G, const float* __restrict__ deg,
                       const float* __restrict__ embW, float* __restrict__ tip) {
  int gid = blockIdx.x;  // r*4096 + i
  int t = threadIdx.x;   // 256
  int r = gid >> 12;
  const float4* row4 = (const float4*)(G + (size_t)gid * NI);
  __shared__ int nz[512];
  __shared__ int cnt;
  __shared__ float4 red[8][32];
  if (t == 0) cnt = 0;
  __syncthreads();
#pragma unroll
  for (int c = 0; c < 4; ++c) {
    int idx4 = c * 256 + t;
    float4 v = row4[idx4];
    int j0 = idx4 << 2;
    if (v.x != 0.f) nz[atomicAdd(&cnt, 1)] = j0;
    if (v.y != 0.f) nz[atomicAdd(&cnt, 1)] = j0 + 1;
    if (v.z != 0.f) nz[atomicAdd(&cnt, 1)] = j0 + 2;
    if (v.w != 0.f) nz[atomicAdd(&cnt, 1)] = j0 + 3;
  }
  __syncthreads();
  int n = min(cnt, 512);
  int g = t >> 5, f = t & 31;  // 8 neighbor-slots x 32 lanes (float4 each)
  float4 acc = {0.f, 0.f, 0.f, 0.f};
  const float4* e4 = (const float4*)(embW + (size_t)r * NI * 128);
  for (int p = g; p < n; p += 8) {
    float4 v = e4[(size_t)nz[p] * 32 + f];
    acc.x += v.x; acc.y += v.y; acc.z += v.z; acc.w += v.w;
  }
  red[g][f] = acc;
  __syncthreads();
  if (t < 32) {
    float4 s = red[0][t];
#pragma unroll
    for (int q = 1; q < 8; ++q) {
      float4 v = red[q][t];
      s.x += v.x; s.y += v.y; s.z += v.z; s.w += v.w;
    }
    float inv = 1.f / (deg[gid] + FEPS);
    s.x *= inv; s.y *= inv; s.z *= inv; s.w *= inv;
    ((float4*)(tip + (size_t)gid * 128))[t] = s;
  }
}

// ---------------------------------------------------------------------------
// K3 k_mid: bid<4096: itemf[i] via bmT column CSC (reads launch-1 outputs).
// bid>=4096 (1536 blocks): per-(b,r) user pipeline (reads launch-1/2 outputs).
__global__ void k_mid(const unsigned long long* __restrict__ bmT,
                      const float* __restrict__ uew, float* __restrict__ itemf,
                      const int* __restrict__ user, const float* __restrict__ relm,
                      const float* __restrict__ si, const float* __restrict__ tip,
                      const float* __restrict__ uemb, const float* __restrict__ WK,
                      const float* __restrict__ BK, const float* __restrict__ ibW,
                      const float* __restrict__ ubd, const float* __restrict__ mw,
                      float* __restrict__ wtun, float* __restrict__ proj) {
  int t = threadIdx.x;  // 256
  int bid = blockIdx.x;
  if (bid < 4096) {
    int i = bid;  // item
    int ct = i >> 6;
    unsigned long long bitm = 1ull << (i & 63);
    __shared__ int lst[192];
    __shared__ int cnt2;
    __shared__ float red2[3][128];
    if (t == 0) cnt2 = 0;
    __syncthreads();
    const unsigned long long* col = bmT + (size_t)ct * NU;
#pragma unroll
    for (int cc = 0; cc < 16; ++cc) {
      unsigned long long m = col[cc * 256 + t];
      if (m & bitm) lst[atomicAdd(&cnt2, 1)] = cc * 256 + t;
    }
    __syncthreads();
    int n = min(cnt2, 192);
    int w = t >> 6, l = t & 63;
    float ax = 0.f, ay = 0.f;
    const float2* uew2 = (const float2*)uew;
    for (int p = w; p < n; p += 4) {
      float2 v = uew2[(size_t)lst[p] * 64 + l];
      ax += v.x; ay += v.y;
    }
    if (w > 0) { red2[w - 1][2 * l] = ax; red2[w - 1][2 * l + 1] = ay; }
    __syncthreads();
    if (w == 0) {
      float2 o;
      o.x = ax + red2[0][2 * l] + red2[1][2 * l] + red2[2][2 * l];
      o.y = ay + red2[0][2 * l + 1] + red2[1][2 * l + 1] + red2[2][2 * l + 1];
      ((float2*)(itemf + (size_t)i * 128))[l] = o;
    }
  } else {
    int ub = bid - 4096;
    int r = ub >> 9, b = ub & 511;
    int u = user[b];
    const float* rel = relm + ((size_t)r * NU + u) * NI;
    __shared__ int nz[512];
    __shared__ int cnt;
    __shared__ __align__(16) float uel[128];
    __shared__ float redA[4][128];
    __shared__ float redB[4][128];
    __shared__ float tu[128];
    if (t == 0) cnt = 0;
    if (t < 32) ((float4*)uel)[t] = ((const float4*)(uemb + (size_t)u * 128))[t];
    __syncthreads();
    const float4* rel4 = (const float4*)rel;
#pragma unroll
    for (int c = 0; c < 4; ++c) {
      int idx4 = c * 256 + t;
      float4 v = rel4[idx4];
      int j0 = idx4 << 2;
      if (v.x != 0.f) nz[atomicAdd(&cnt, 1)] = j0;
      if (v.y != 0.f) nz[atomicAdd(&cnt, 1)] = j0 + 1;
      if (v.z != 0.f) nz[atomicAdd(&cnt, 1)] = j0 + 2;
      if (v.w != 0.f) nz[atomicAdd(&cnt, 1)] = j0 + 3;
    }
    __syncthreads();
    int n = min(cnt, 512);
    int wid = t >> 6, lane = t & 63;
    int k = lane >> 4;  // head: 16 lanes per head, float2 per lane covers D=32
    float2 myue = ((const float2*)uel)[lane];
    float sux = 0.f, suy = 0.f, tpx = 0.f, tpy = 0.f;
    const float2* si2 = (const float2*)si;
    const float2* tip2 = (const float2*)(tip + (size_t)r * NI * 128);
    for (int p = wid; p < n; p += 4) {
      int i = nz[p];
      float2 sv = si2[(size_t)i * 64 + lane];
      float lg = myue.x * sv.x + myue.y * sv.y;
      lg += __shfl_xor(lg, 1);
      lg += __shfl_xor(lg, 2);
      lg += __shfl_xor(lg, 4);
      lg += __shfl_xor(lg, 8);
      float l0 = __shfl(lg, 0), l1 = __shfl(lg, 16), l2 = __shfl(lg, 32), l3 = __shfl(lg, 48);
      float mx = fmaxf(fmaxf(l0, l1), fmaxf(l2, l3));
      float e0 = __expf(l0 - mx), e1 = __expf(l1 - mx), e2 = __expf(l2 - mx), e3 = __expf(l3 - mx);
      float inv = 1.f / (e0 + e1 + e2 + e3);
      float myr = (k == 0 ? e0 : k == 1 ? e1 : k == 2 ? e2 : e3) * inv;
      sux += myr * sv.x;
      suy += myr * sv.y;
      float2 tv = tip2[(size_t)i * 64 + lane];
      tpx += tv.x;
      tpy += tv.y;
    }
    redA[wid][2 * lane] = sux; redA[wid][2 * lane + 1] = suy;
    redB[wid][2 * lane] = tpx; redB[wid][2 * lane + 1] = tpy;
    __syncthreads();
    if (t < 128) {
      float suv = redA[0][t] + redA[1][t] + redA[2][t] + redA[3][t];
      float tipv = redB[0][t] + redB[1][t] + redB[2][t] + redB[3][t];
      float a = BK[t];
      const float4* wk4 = (const float4*)(WK + (size_t)t * 128);
      const float4* ue4 = (const float4*)uel;
#pragma unroll 8
      for (int c = 0; c < 32; ++c) {
        float4 w = wk4[c], v = ue4[c];
        a += w.x * v.x + w.y * v.y + w.z * v.z + w.w * v.w;
      }
      a = fmaxf(a, 0.f);
      float sq = a * a;
#pragma unroll
      for (int m = 1; m <= 16; m <<= 1) sq += __shfl_xor(sq, m);
      float su = a / fmaxf(sqrtf(sq), 1e-12f) + suv;
      float sq2 = su * su;
#pragma unroll
      for (int m = 1; m <= 16; m <<= 1) sq2 += __shfl_xor(sq2, m);
      float tun = su / fmaxf(sqrtf(sq2), 1e-12f);
      float d0 = ubd[u * 3], d1 = ubd[u * 3 + 1], d2 = ubd[u * 3 + 2];
      float w0 = mw[0], w1 = mw[1], w2 = mw[2];
      float tw = d0 * w0 + d1 * w1 + d2 * w2;
      float dr = (r == 0 ? d0 : r == 1 ? d1 : d2);
      float wr = (r == 0 ? w0 : r == 1 ? w1 : w2);
      wtun[(size_t)(b * 3 + r) * 128 + t] = (dr * wr / (tw + FEPS)) * tun;
      tu[t] = tipv / (dr + FEPS);
    }
    __syncthreads();
    int ep = t & 127, hh = t >> 7;
    const float* Wb = ibW + (size_t)r * 16384;
    float pacc = 0.f;
    for (int e = hh * 64; e < hh * 64 + 64; ++e) pacc += tu[e] * Wb[e * 128 + ep];
    redA[hh][ep] = pacc;
    __syncthreads();
    if (hh == 0) proj[(size_t)(b * 3 + r) * 128 + ep] = redA[0][ep] + redA[1][ep];
  }
}

// ---------------------------------------------------------------------------
// K4: uf[b] = (sum_r wtun[b,r]) @ W ; per-b uf^2 partial
__global__ void k_uf(const float* __restrict__ wtun, const float* __restrict__ Wm,
                     float* __restrict__ uf, float* __restrict__ uf2p) {
  int b = blockIdx.x, t = threadIdx.x;  // 128
  __shared__ float comb[128];
  __shared__ float part[2];
  comb[t] = wtun[(size_t)(b * 3) * 128 + t] + wtun[(size_t)(b * 3 + 1) * 128 + t] +
            wtun[(size_t)(b * 3 + 2) * 128 + t];
  __syncthreads();
  float acc = 0.f;
  for (int e = 0; e < 128; ++e) acc += comb[e] * Wm[e * 128 + t];
  uf[(size_t)b * 128 + t] = acc;
  float sq = acc * acc;
#pragma unroll
  for (int m = 1; m <= 32; m <<= 1) sq += __shfl_xor(sq, m);
  if ((t & 63) == 0) part[t >> 6] = sq;
  __syncthreads();
  if (t == 0) uf2p[b] = part[0] + part[1];
}

// ---------------------------------------------------------------------------
// K5: one wave per (b,l): score1 + LAMB*score2/R ; itf^2 partial per block
__global__ void k_score(const int* __restrict__ item, const float* __restrict__ itemf,
                        const float* __restrict__ uf, const float* __restrict__ tip,
                        const float* __restrict__ proj, float* __restrict__ out,
                        float* __restrict__ itf2p) {
  int t = threadIdx.x, wid = t >> 6, lane = t & 63;
  int idx = blockIdx.x * 4 + wid;  // < 51200
  int b = idx / NL;
  int it = item[idx];
  float2 av = ((const float2*)(itemf + (size_t)it * 128))[lane];
  float2 cv = ((const float2*)(uf + (size_t)b * 128))[lane];
  float s1 = av.x * cv.x + av.y * cv.y;
  float sqi = av.x * av.x + av.y * av.y;
  float s2 = 0.f;
#pragma unroll
  for (int r = 0; r < 3; ++r) {
    float2 tv = ((const float2*)(tip + ((size_t)r * NI + it) * 128))[lane];
    float2 pv = ((const float2*)(proj + (size_t)(b * 3 + r) * 128))[lane];
    s2 += tv.x * pv.x + tv.y * pv.y;
  }
#pragma unroll
  for (int m = 1; m <= 32; m <<= 1) {
    s1 += __shfl_xor(s1, m);
    s2 += __shfl_xor(s2, m);
    sqi += __shfl_xor(sqi, m);
  }
  if (lane == 0) out[idx] = s1 + 0.5f * (s2 * (1.f / 3.f));
  __shared__ float sh[4];
  if (lane == 0) sh[wid] = sqi;
  __syncthreads();
  if (t == 0) itf2p[blockIdx.x] = sh[0] + sh[1] + sh[2] + sh[3];
}

// ---------------------------------------------------------------------------
// K6: L2_loss = 1e-4 * (100 * sum uf^2 + sum itf^2)
__global__ void k_final(const float* __restrict__ itf2p, const float* __restrict__ uf2p,
                        float* __restrict__ out) {
  int t = threadIdx.x;  // 256
  float v = 0.f;
  for (int i = t; i < 12800; i += 256) v += itf2p[i];
  float vu = 0.f;
  for (int i = t; i < NB; i += 256) vu += uf2p[i];
  v += 100.f * vu;
#pragma unroll
  for (int m = 1; m <= 32; m <<= 1) v += __shfl_xor(v, m);
  __shared__ float sh[4];
  if ((t & 63) == 0) sh[t >> 6] = v;
  __syncthreads();
  if (t == 0) out[NB * NL] = 1e-4f * (sh[0] + sh[1] + sh[2] + sh[3]);
}

// ---------------------------------------------------------------------------
extern "C" void kernel_launch(void* const* d_in, const int* in_sizes, int n_in,
                              void* d_out, int out_size, void* d_ws, size_t ws_size,
                              hipStream_t stream) {
  (void)in_sizes; (void)n_in; (void)out_size; (void)ws_size;
  const int* user = (const int*)d_in[0];
  const int* item = (const int*)d_in[1];
  const float* uemb = (const float*)d_in[2];
  const float* iemb = (const float*)d_in[3];
  const float* mw = (const float*)d_in[4];
  const float* ibW = (const float*)d_in[5];
  const float* ipW = (const float*)d_in[6];
  const float* Wm = (const float*)d_in[7];
  const float* WK = (const float*)d_in[8];
  const float* BK = (const float*)d_in[9];
  const float* tm = (const float*)d_in[10];
  const float* relm = (const float*)d_in[11];
  const float* ig = (const float*)d_in[12];
  const float* igd = (const float*)d_in[13];
  const float* ubd = (const float*)d_in[14];
  float* out = (float*)d_out;
  float* ws = (float*)d_ws;
  unsigned long long* bmT = (unsigned long long*)(ws + WS_BMT);

  k_prep<<<7168, 256, 0, stream>>>(iemb, ipW, uemb, Wm, WK, BK, tm,
                                   ws + WS_EMBW, ws + WS_UEW, ws + WS_SI, bmT);
  k_scan<<<NR * NI, 256, 0, stream>>>(ig, igd, ws + WS_EMBW, ws + WS_TIP);
  k_mid<<<5632, 256, 0, stream>>>(bmT, ws + WS_UEW, ws + WS_ITEMF, user, relm,
                                  ws + WS_SI, ws + WS_TIP, uemb, WK, BK, ibW,
                                  ubd, mw, ws + WS_WTUN, ws + WS_PROJ);
  k_uf<<<NB, 128, 0, stream>>>(ws + WS_WTUN, Wm, ws + WS_UF, ws + WS_UF2P);
  k_score<<<12800, 256, 0, stream>>>(item, ws + WS_ITEMF, ws + WS_UF, ws + WS_TIP,
                                     ws + WS_PROJ, out, ws + WS_ITF2P);
  k_final<<<1, 256, 0, stream>>>(ws + WS_ITF2P, ws + WS_UF2P, out);
}

// Round 11
// 186.339 us; speedup vs baseline: 1.9046x; 1.0271x over previous
//
#include <hip/hip_runtime.h>

#define NU 4096
#define NI 4096
#define NR 3
#define NB 512
#define NL 100
#define FEPS 1e-8f

// workspace layout (float offsets)
#define WS_SI    0            // [NI*128]   s_i: [i][k*32+d]
#define WS_EMBW  524288       // [3*NI*128] iemb @ ipW[r]
#define WS_TIP   2097152      // [3*NI*128] tip per relation
#define WS_UEW   3670016      // [NU*128]   user_embedding @ W
#define WS_ITEMF 4194304      // [NI*128]   item_feature
#define WS_WTUN  4718592      // [NB*3*128] ubw-weighted tun per (b,r)
#define WS_PROJ  4915200      // [NB*3*128] proj per (b,r)
#define WS_UF    5111808      // [NB*128]   uf_sel
#define WS_UF2P  5177344      // [NB]       per-b uf^2 partials
#define WS_ITF2P 5177856      // [12800]    per-block itf^2 partials
#define WS_BMT   5190656      // [64*4096 ulong = 2MB] bit-columns of tm (ballot layout)
#define WS_GBITS 5714944      // [12288*64 ulong = 6MB] bit-rows of item_graphs (ballot layout)

// Ballot bit layout: for a 256-element chunk, word q (q=0..3) bit l (l=0..63)
// <=> element chunk*256 + 4*l + q.

// ---------------------------------------------------------------------------
// K1 k_front: bid<1024: batched GEMM (b0-2 embW[r]=iemb@ipW[r], b3 uew=uemb@W);
// bid<3072: s_i for 2 items/block; bid<5120: persistent ballot scan of
// tm (rows 0..4095) + G (rows 4096..16383) -> bmT + gbits (R6 k_scan2 verbatim).
__global__ void k_front(const float* __restrict__ iemb, const float* __restrict__ ipW,
                        const float* __restrict__ uemb, const float* __restrict__ Wm,
                        const float* __restrict__ WK, const float* __restrict__ BK,
                        const float* __restrict__ tm, const float* __restrict__ G,
                        float* __restrict__ embW, float* __restrict__ uew,
                        float* __restrict__ si,
                        unsigned long long* __restrict__ bmT,
                        unsigned long long* __restrict__ gbits) {
  int t = threadIdx.x;  // 256
  int bid = blockIdx.x;
  if (bid < 1024) {
    __shared__ __align__(16) float shbuf[2048];
    int batch = bid >> 8, rb = bid & 255;  // 16 rows per block
    const float* in;
    const float* Wp;
    float* outp;
    if (batch < 3) {
      in = iemb;
      Wp = ipW + (size_t)batch * 16384;
      outp = embW + (size_t)batch * NI * 128;
    } else {
      in = uemb; Wp = Wm; outp = uew;
    }
    const float4* in4 = (const float4*)(in + (size_t)rb * 2048);
    for (int c = t; c < 512; c += 256) ((float4*)shbuf)[c] = in4[c];
    __syncthreads();
    int c = t & 127, g = t >> 7;
    float acc[8];
#pragma unroll
    for (int rr = 0; rr < 8; ++rr) acc[rr] = 0.f;
    for (int e = 0; e < 128; ++e) {
      float wv = Wp[e * 128 + c];
#pragma unroll
      for (int rr = 0; rr < 8; ++rr) acc[rr] += shbuf[(g * 8 + rr) * 128 + e] * wv;
    }
#pragma unroll
    for (int rr = 0; rr < 8; ++rr) outp[((size_t)rb * 16 + g * 8 + rr) * 128 + c] = acc[rr];
  } else if (bid < 3072) {
    __shared__ __align__(16) float embs2[256];
    int tl = t & 127, half = t >> 7;
    int item = (bid - 1024) * 2 + half;
    float* embs = embs2 + half * 128;
    if (tl < 32) ((float4*)embs)[tl] = ((const float4*)(iemb + (size_t)item * 128))[tl];
    __syncthreads();
    float acc = BK[tl];
    const float4* wk4 = (const float4*)(WK + (size_t)tl * 128);
    const float4* e4 = (const float4*)embs;
#pragma unroll 8
    for (int cc = 0; cc < 32; ++cc) {
      float4 w = wk4[cc], v = e4[cc];
      acc += w.x * v.x + w.y * v.y + w.z * v.z + w.w * v.w;
    }
    acc = fmaxf(acc, 0.f);
    float sq = acc * acc;
#pragma unroll
    for (int m = 1; m <= 16; m <<= 1) sq += __shfl_xor(sq, m);
    si[(size_t)item * 128 + tl] = acc / fmaxf(sqrtf(sq), 1e-12f);
  } else {
    // persistent ballot scan: 2048 blocks x 4 waves; 65536 (row, chunk-quad) tasks
    int wid = ((bid - 3072) << 2) + (t >> 6);  // 0..8191
    int lane = t & 63;
    for (int task = wid; task < 65536; task += 8192) {
      int row = task >> 2;
      int cq = (task & 3) << 2;  // first chunk (of 4) handled by this task
      const float* src = (row < NU) ? (tm + (size_t)row * NI)
                                    : (G + (size_t)(row - NU) * NI);
      const float4* s4 = (const float4*)src + (cq << 6) + lane;
      float4 v0 = s4[0];
      float4 v1 = s4[64];
      float4 v2 = s4[128];
      float4 v3 = s4[192];
      unsigned long long a0 = __ballot(v0.x != 0.f), a1 = __ballot(v0.y != 0.f),
                         a2 = __ballot(v0.z != 0.f), a3 = __ballot(v0.w != 0.f);
      unsigned long long b0 = __ballot(v1.x != 0.f), b1 = __ballot(v1.y != 0.f),
                         b2 = __ballot(v1.z != 0.f), b3 = __ballot(v1.w != 0.f);
      unsigned long long c0 = __ballot(v2.x != 0.f), c1 = __ballot(v2.y != 0.f),
                         c2 = __ballot(v2.z != 0.f), c3 = __ballot(v2.w != 0.f);
      unsigned long long d0 = __ballot(v3.x != 0.f), d1 = __ballot(v3.y != 0.f),
                         d2 = __ballot(v3.z != 0.f), d3 = __ballot(v3.w != 0.f);
      if (lane == 0) {
        if (row < NU) {
          // bmT word index = (chunk*4+q)*4096 + row
          size_t base = ((size_t)cq << 14) + row;
          bmT[base] = a0;                bmT[base + (1 << 12)] = a1;
          bmT[base + (2 << 12)] = a2;    bmT[base + (3 << 12)] = a3;
          size_t b1b = base + (1 << 14);
          bmT[b1b] = b0;                 bmT[b1b + (1 << 12)] = b1;
          bmT[b1b + (2 << 12)] = b2;     bmT[b1b + (3 << 12)] = b3;
          size_t b2b = base + (2 << 14);
          bmT[b2b] = c0;                 bmT[b2b + (1 << 12)] = c1;
          bmT[b2b + (2 << 12)] = c2;     bmT[b2b + (3 << 12)] = c3;
          size_t b3b = base + (3 << 14);
          bmT[b3b] = d0;                 bmT[b3b + (1 << 12)] = d1;
          bmT[b3b + (2 << 12)] = d2;     bmT[b3b + (3 << 12)] = d3;
        } else {
          // gbits[grow][chunk*4+q], contiguous 128 B per task
          unsigned long long* g = gbits + (((size_t)(row - NU)) << 6) + (cq << 2);
          g[0] = a0;  g[1] = a1;  g[2] = a2;  g[3] = a3;
          g[4] = b0;  g[5] = b1;  g[6] = b2;  g[7] = b3;
          g[8] = c0;  g[9] = c1;  g[10] = c2; g[11] = c3;
          g[12] = d0; g[13] = d1; g[14] = d2; g[15] = d3;
        }
      }
    }
  }
}

// ---------------------------------------------------------------------------
// K2 k_gather: bid<12288: tip[r][i] = (gather embW[r] over gbits row)/(deg+eps)
//              bid>=12288: itemf[i] = sum uew[u] over bmT column (CSC)
__global__ void k_gather(const unsigned long long* __restrict__ gbits,
                         const unsigned long long* __restrict__ bmT,
                         const float* __restrict__ embW, const float* __restrict__ uew,
                         const float* __restrict__ deg,
                         float* __restrict__ tip, float* __restrict__ itemf) {
  int t = threadIdx.x;  // 256
  int bid = blockIdx.x;
  if (bid < 12288) {
    int r = bid >> 12;
    __shared__ int nz[512];
    __shared__ int cnt;
    __shared__ float4 red[8][32];
    if (t == 0) cnt = 0;
    __syncthreads();
    if (t < 64) {
      unsigned long long m = gbits[(size_t)bid * 64 + t];
      int base = ((t >> 2) << 8) + (t & 3);  // chunk*256 + q
      while (m) {
        int b = __ffsll(m) - 1;
        m &= m - 1;
        nz[atomicAdd(&cnt, 1)] = base + (b << 2);
      }
    }
    __syncthreads();
    int n = min(cnt, 512);
    int g = t >> 5, f = t & 31;  // 8 neighbor-slots x 32 lanes (float4 each)
    float4 acc = {0.f, 0.f, 0.f, 0.f};
    const float4* e4 = (const float4*)(embW + (size_t)r * NI * 128);
    for (int p = g; p < n; p += 8) {
      float4 v = e4[(size_t)nz[p] * 32 + f];
      acc.x += v.x; acc.y += v.y; acc.z += v.z; acc.w += v.w;
    }
    red[g][f] = acc;
    __syncthreads();
    if (t < 32) {
      float4 s = red[0][t];
#pragma unroll
      for (int q = 1; q < 8; ++q) {
        float4 v = red[q][t];
        s.x += v.x; s.y += v.y; s.z += v.z; s.w += v.w;
      }
      float inv = 1.f / (deg[bid] + FEPS);
      s.x *= inv; s.y *= inv; s.z *= inv; s.w *= inv;
      ((float4*)(tip + (size_t)bid * 128))[t] = s;
    }
  } else {
    int i = bid - 12288;  // item
    int chunk = i >> 8, w8 = i & 255, q = w8 & 3, l = w8 >> 2;
    unsigned long long bitm = 1ull << l;
    __shared__ int lst[192];
    __shared__ int cnt2;
    __shared__ float red2[3][128];
    if (t == 0) cnt2 = 0;
    __syncthreads();
    const unsigned long long* col = bmT + (((size_t)(chunk << 2) + q) << 12);
#pragma unroll
    for (int cc = 0; cc < 16; ++cc) {
      unsigned long long m = col[cc * 256 + t];
      if (m & bitm) lst[atomicAdd(&cnt2, 1)] = cc * 256 + t;
    }
    __syncthreads();
    int n = min(cnt2, 192);
    int w = t >> 6, l2 = t & 63;
    float ax = 0.f, ay = 0.f;
    const float2* uew2 = (const float2*)uew;
    for (int p = w; p < n; p += 4) {
      float2 v = uew2[(size_t)lst[p] * 64 + l2];
      ax += v.x; ay += v.y;
    }
    if (w > 0) { red2[w - 1][2 * l2] = ax; red2[w - 1][2 * l2 + 1] = ay; }
    __syncthreads();
    if (w == 0) {
      float2 o;
      o.x = ax + red2[0][2 * l2] + red2[1][2 * l2] + red2[2][2 * l2];
      o.y = ay + red2[0][2 * l2 + 1] + red2[1][2 * l2 + 1] + red2[2][2 * l2 + 1];
      ((float2*)(itemf + (size_t)i * 128))[l2] = o;
    }
  }
}

// ---------------------------------------------------------------------------
// K3 k_user: per (b,r): rel-row scan, on-the-fly softmax over K per neighbor,
// accumulate s_u and rel@tip; emit ubw-weighted tun and proj. (R10 verbatim.)
__global__ void k_user(const int* __restrict__ user, const float* __restrict__ relm,
                       const float* __restrict__ si, const float* __restrict__ tip,
                       const float* __restrict__ uemb, const float* __restrict__ WK,
                       const float* __restrict__ BK, const float* __restrict__ ibW,
                       const float* __restrict__ ubd, const float* __restrict__ mw,
                       float* __restrict__ wtun, float* __restrict__ proj) {
  int ub = blockIdx.x;
  int r = ub >> 9, b = ub & 511;
  int t = threadIdx.x;  // 256
  int u = user[b];
  const float* rel = relm + ((size_t)r * NU + u) * NI;
  __shared__ int nz[512];
  __shared__ int cnt;
  __shared__ __align__(16) float uel[128];
  __shared__ float redA[4][128];
  __shared__ float redB[4][128];
  __shared__ float tu[128];
  if (t == 0) cnt = 0;
  if (t < 32) ((float4*)uel)[t] = ((const float4*)(uemb + (size_t)u * 128))[t];
  __syncthreads();
  const float4* rel4 = (const float4*)rel;
#pragma unroll
  for (int c = 0; c < 4; ++c) {
    int idx4 = c * 256 + t;
    float4 v = rel4[idx4];
    int j0 = idx4 << 2;
    if (v.x != 0.f) nz[atomicAdd(&cnt, 1)] = j0;
    if (v.y != 0.f) nz[atomicAdd(&cnt, 1)] = j0 + 1;
    if (v.z != 0.f) nz[atomicAdd(&cnt, 1)] = j0 + 2;
    if (v.w != 0.f) nz[atomicAdd(&cnt, 1)] = j0 + 3;
  }
  __syncthreads();
  int n = min(cnt, 512);
  int wid = t >> 6, lane = t & 63;
  int k = lane >> 4;  // head: 16 lanes per head, float2 per lane covers D=32
  float2 myue = ((const float2*)uel)[lane];
  float sux = 0.f, suy = 0.f, tpx = 0.f, tpy = 0.f;
  const float2* si2 = (const float2*)si;
  const float2* tip2 = (const float2*)(tip + (size_t)r * NI * 128);
  for (int p = wid; p < n; p += 4) {
    int i = nz[p];
    float2 sv = si2[(size_t)i * 64 + lane];
    float lg = myue.x * sv.x + myue.y * sv.y;
    lg += __shfl_xor(lg, 1);
    lg += __shfl_xor(lg, 2);
    lg += __shfl_xor(lg, 4);
    lg += __shfl_xor(lg, 8);
    float l0 = __shfl(lg, 0), l1 = __shfl(lg, 16), l2 = __shfl(lg, 32), l3 = __shfl(lg, 48);
    float mx = fmaxf(fmaxf(l0, l1), fmaxf(l2, l3));
    float e0 = __expf(l0 - mx), e1 = __expf(l1 - mx), e2 = __expf(l2 - mx), e3 = __expf(l3 - mx);
    float inv = 1.f / (e0 + e1 + e2 + e3);
    float myr = (k == 0 ? e0 : k == 1 ? e1 : k == 2 ? e2 : e3) * inv;
    sux += myr * sv.x;
    suy += myr * sv.y;
    float2 tv = tip2[(size_t)i * 64 + lane];
    tpx += tv.x;
    tpy += tv.y;
  }
  redA[wid][2 * lane] = sux; redA[wid][2 * lane + 1] = suy;
  redB[wid][2 * lane] = tpx; redB[wid][2 * lane + 1] = tpy;
  __syncthreads();
  if (t < 128) {
    float suv = redA[0][t] + redA[1][t] + redA[2][t] + redA[3][t];
    float tipv = redB[0][t] + redB[1][t] + redB[2][t] + redB[3][t];
    float a = BK[t];
    const float4* wk4 = (const float4*)(WK + (size_t)t * 128);
    const float4* ue4 = (const float4*)uel;
#pragma unroll 8
    for (int c = 0; c < 32; ++c) {
      float4 w = wk4[c], v = ue4[c];
      a += w.x * v.x + w.y * v.y + w.z * v.z + w.w * v.w;
    }
    a = fmaxf(a, 0.f);
    float sq = a * a;
#pragma unroll
    for (int m = 1; m <= 16; m <<= 1) sq += __shfl_xor(sq, m);
    float su = a / fmaxf(sqrtf(sq), 1e-12f) + suv;
    float sq2 = su * su;
#pragma unroll
    for (int m = 1; m <= 16; m <<= 1) sq2 += __shfl_xor(sq2, m);
    float tun = su / fmaxf(sqrtf(sq2), 1e-12f);
    float d0 = ubd[u * 3], d1 = ubd[u * 3 + 1], d2 = ubd[u * 3 + 2];
    float w0 = mw[0], w1 = mw[1], w2 = mw[2];
    float tw = d0 * w0 + d1 * w1 + d2 * w2;
    float dr = (r == 0 ? d0 : r == 1 ? d1 : d2);
    float wr = (r == 0 ? w0 : r == 1 ? w1 : w2);
    wtun[(size_t)(b * 3 + r) * 128 + t] = (dr * wr / (tw + FEPS)) * tun;
    tu[t] = tipv / (dr + FEPS);
  }
  __syncthreads();
  int ep = t & 127, hh = t >> 7;
  const float* Wb = ibW + (size_t)r * 16384;
  float pacc = 0.f;
  for (int e = hh * 64; e < hh * 64 + 64; ++e) pacc += tu[e] * Wb[e * 128 + ep];
  redA[hh][ep] = pacc;
  __syncthreads();
  if (hh == 0) proj[(size_t)(b * 3 + r) * 128 + ep] = redA[0][ep] + redA[1][ep];
}

// ---------------------------------------------------------------------------
// K4: uf[b] = (sum_r wtun[b,r]) @ W ; per-b uf^2 partial
__global__ void k_uf(const float* __restrict__ wtun, const float* __restrict__ Wm,
                     float* __restrict__ uf, float* __restrict__ uf2p) {
  int b = blockIdx.x, t = threadIdx.x;  // 128
  __shared__ float comb[128];
  __shared__ float part[2];
  comb[t] = wtun[(size_t)(b * 3) * 128 + t] + wtun[(size_t)(b * 3 + 1) * 128 + t] +
            wtun[(size_t)(b * 3 + 2) * 128 + t];
  __syncthreads();
  float acc = 0.f;
  for (int e = 0; e < 128; ++e) acc += comb[e] * Wm[e * 128 + t];
  uf[(size_t)b * 128 + t] = acc;
  float sq = acc * acc;
#pragma unroll
  for (int m = 1; m <= 32; m <<= 1) sq += __shfl_xor(sq, m);
  if ((t & 63) == 0) part[t >> 6] = sq;
  __syncthreads();
  if (t == 0) uf2p[b] = part[0] + part[1];
}

// ---------------------------------------------------------------------------
// K5: one wave per (b,l): score1 + LAMB*score2/R ; itf^2 partial per block
__global__ void k_score(const int* __restrict__ item, const float* __restrict__ itemf,
                        const float* __restrict__ uf, const float* __restrict__ tip,
                        const float* __restrict__ proj, float* __restrict__ out,
                        float* __restrict__ itf2p) {
  int t = threadIdx.x, wid = t >> 6, lane = t & 63;
  int idx = blockIdx.x * 4 + wid;  // < 51200
  int b = idx / NL;
  int it = item[idx];
  float2 av = ((const float2*)(itemf + (size_t)it * 128))[lane];
  float2 cv = ((const float2*)(uf + (size_t)b * 128))[lane];
  float s1 = av.x * cv.x + av.y * cv.y;
  float sqi = av.x * av.x + av.y * av.y;
  float s2 = 0.f;
#pragma unroll
  for (int r = 0; r < 3; ++r) {
    float2 tv = ((const float2*)(tip + ((size_t)r * NI + it) * 128))[lane];
    float2 pv = ((const float2*)(proj + (size_t)(b * 3 + r) * 128))[lane];
    s2 += tv.x * pv.x + tv.y * pv.y;
  }
#pragma unroll
  for (int m = 1; m <= 32; m <<= 1) {
    s1 += __shfl_xor(s1, m);
    s2 += __shfl_xor(s2, m);
    sqi += __shfl_xor(sqi, m);
  }
  if (lane == 0) out[idx] = s1 + 0.5f * (s2 * (1.f / 3.f));
  __shared__ float sh[4];
  if (lane == 0) sh[wid] = sqi;
  __syncthreads();
  if (t == 0) itf2p[blockIdx.x] = sh[0] + sh[1] + sh[2] + sh[3];
}

// ---------------------------------------------------------------------------
// K6: L2_loss = 1e-4 * (100 * sum uf^2 + sum itf^2)
__global__ void k_final(const float* __restrict__ itf2p, const float* __restrict__ uf2p,
                        float* __restrict__ out) {
  int t = threadIdx.x;  // 256
  float v = 0.f;
  for (int i = t; i < 12800; i += 256) v += itf2p[i];
  float vu = 0.f;
  for (int i = t; i < NB; i += 256) vu += uf2p[i];
  v += 100.f * vu;
#pragma unroll
  for (int m = 1; m <= 32; m <<= 1) v += __shfl_xor(v, m);
  __shared__ float sh[4];
  if ((t & 63) == 0) sh[t >> 6] = v;
  __syncthreads();
  if (t == 0) out[NB * NL] = 1e-4f * (sh[0] + sh[1] + sh[2] + sh[3]);
}

// ---------------------------------------------------------------------------
extern "C" void kernel_launch(void* const* d_in, const int* in_sizes, int n_in,
                              void* d_out, int out_size, void* d_ws, size_t ws_size,
                              hipStream_t stream) {
  (void)in_sizes; (void)n_in; (void)out_size; (void)ws_size;
  const int* user = (const int*)d_in[0];
  const int* item = (const int*)d_in[1];
  const float* uemb = (const float*)d_in[2];
  const float* iemb = (const float*)d_in[3];
  const float* mw = (const float*)d_in[4];
  const float* ibW = (const float*)d_in[5];
  const float* ipW = (const float*)d_in[6];
  const float* Wm = (const float*)d_in[7];
  const float* WK = (const float*)d_in[8];
  const float* BK = (const float*)d_in[9];
  const float* tm = (const float*)d_in[10];
  const float* relm = (const float*)d_in[11];
  const float* ig = (const float*)d_in[12];
  const float* igd = (const float*)d_in[13];
  const float* ubd = (const float*)d_in[14];
  float* out = (float*)d_out;
  float* ws = (float*)d_ws;
  unsigned long long* bmT = (unsigned long long*)(ws + WS_BMT);
  unsigned long long* gbits = (unsigned long long*)(ws + WS_GBITS);

  k_front<<<5120, 256, 0, stream>>>(iemb, ipW, uemb, Wm, WK, BK, tm, ig,
                                    ws + WS_EMBW, ws + WS_UEW, ws + WS_SI, bmT, gbits);
  k_gather<<<16384, 256, 0, stream>>>(gbits, bmT, ws + WS_EMBW, ws + WS_UEW, igd,
                                      ws + WS_TIP, ws + WS_ITEMF);
  k_user<<<1536, 256, 0, stream>>>(user, relm, ws + WS_SI, ws + WS_TIP, uemb, WK, BK,
                                   ibW, ubd, mw, ws + WS_WTUN, ws + WS_PROJ);
  k_uf<<<NB, 128, 0, stream>>>(ws + WS_WTUN, Wm, ws + WS_UF, ws + WS_UF2P);
  k_score<<<12800, 256, 0, stream>>>(item, ws + WS_ITEMF, ws + WS_UF, ws + WS_TIP,
                                     ws + WS_PROJ, out, ws + WS_ITF2P);
  k_final<<<1, 256, 0, stream>>>(ws + WS_ITF2P, ws + WS_UF2P, out);
}